// Round 16
// baseline (212.044 us; speedup 1.0000x reference)
//
#include <hip/hip_runtime.h>
#include <hip/hip_bf16.h>

// Problem constants (fixed by the reference)
#define BB 4
#define TT 1024
#define DD 1024
#define HH 16
#define HDIM 64
#define MM (BB*TT)          // 4096

typedef unsigned short u16;
typedef unsigned int u32;
typedef __attribute__((ext_vector_type(8))) short bf16x8;     // 8 bf16 = 4 VGPRs
typedef __attribute__((ext_vector_type(8))) _Float16 f16x8;   // 8 fp16 = 4 VGPRs
typedef __attribute__((ext_vector_type(4))) float f32x4;
typedef __attribute__((ext_vector_type(4))) unsigned short u16x4;
typedef __attribute__((ext_vector_type(2))) unsigned int u32x2;

__device__ __forceinline__ u16 f2bf(float f) {
    union { float f; unsigned u; } v; v.f = f;
    return (u16)((v.u + 0x7fffu + ((v.u >> 16) & 1u)) >> 16);   // RNE
}
__device__ __forceinline__ float bf2f(u16 h) {
    union { unsigned u; float f; } v; v.u = ((unsigned)h) << 16; return v.f;
}
__device__ __forceinline__ u16 f2h(float f) {
    union { _Float16 h; u16 u; } v; v.h = (_Float16)f;          // v_cvt_f16_f32 RNE
    return v.u;
}

// async global->LDS, 16B per lane; lds dest = wave-uniform base + lane*16
__device__ __forceinline__ void gload16(const void* g, void* l) {
    __builtin_amdgcn_global_load_lds(
        (const __attribute__((address_space(1))) unsigned int*)g,
        (__attribute__((address_space(3))) unsigned int*)l, 16, 0, 0);
}

__device__ __forceinline__ void cvt_body(const float* __restrict__ src,
                                         u16* __restrict__ dst,
                                         int bid, bool to_fp16)
{
    const size_t i = ((size_t)bid * 256 + threadIdx.x) * 4;
    const float4 v = *(const float4*)&src[i];
    u16x4 o;
    if (to_fp16) { o[0] = f2h(v.x); o[1] = f2h(v.y); o[2] = f2h(v.z); o[3] = f2h(v.w); }
    else         { o[0] = f2bf(v.x); o[1] = f2bf(v.y); o[2] = f2bf(v.z); o[3] = f2bf(v.w); }
    *(u16x4*)&dst[i] = o;
}

// single fused conversion kernel: x,pe,Wc,Wp -> fp16; Wo -> bf16
__global__ __launch_bounds__(256)
void cvt_all_kernel(const float* __restrict__ x,  u16* __restrict__ x16,
                    const float* __restrict__ pe, u16* __restrict__ pe16,
                    const float* __restrict__ Wc, u16* __restrict__ Wc16,
                    const float* __restrict__ Wp, u16* __restrict__ Wp16,
                    const float* __restrict__ Wo, u16* __restrict__ Wo16)
{
    const int bid = blockIdx.x;
    if (bid < 4096)       cvt_body(x,  x16,  bid,        true);
    else if (bid < 8192)  cvt_body(pe, pe16, bid - 4096, true);
    else if (bid < 10240) cvt_body(Wc, Wc16, bid - 8192, true);
    else if (bid < 11264) cvt_body(Wp, Wp16, bid - 10240, true);
    else                  cvt_body(Wo, Wo16, bid - 11264, false);
}

// k16 [b][h][t][64] -> k16T [b][h][d][1024]   (per-head 64-col transpose)
__global__ __launch_bounds__(256)
void ktrans_kernel(const u16* __restrict__ k16, u16* __restrict__ k16T)
{
    __shared__ u16 tmp[64][72];
    const int tc = blockIdx.x, h = blockIdx.y, b = blockIdx.z;
    const size_t hb = ((size_t)(b * HH + h)) << 16;
    const int tid = threadIdx.x;
    const int sr = tid >> 2, sc = (tid & 3) * 8;
    *(bf16x8*)&tmp[sr][sc]      = *(const bf16x8*)&k16[hb + (size_t)(tc * 64 + sr) * HDIM + sc];
    *(bf16x8*)&tmp[sr][sc + 32] = *(const bf16x8*)&k16[hb + (size_t)(tc * 64 + sr) * HDIM + sc + 32];
    __syncthreads();
#pragma unroll
    for (int half = 0; half < 2; ++half) {
        bf16x8 v;
#pragma unroll
        for (int j = 0; j < 8; ++j) v[j] = (short)tmp[sc + half * 32 + j][sr];
        *(bf16x8*)&k16T[hb + (size_t)sr * TT + tc * 64 + sc + half * 32] = v;
    }
}

// ---------------------------------------------------------------------------
// MFMA GEMM: C = A @ B^T + bias (unchanged from round 12).
// ---------------------------------------------------------------------------
template<bool FP16, int MODE>
__global__ __launch_bounds__(256)
void gemm_mfma(const u16* __restrict__ Ah, const u16* __restrict__ Bh,
               const float* __restrict__ bias,
               float* __restrict__ dstF, u16* __restrict__ dstH1,
               const u16* __restrict__ kaux16,
               const int M, const int N, const int K)
{
    __shared__ u16 As[128][64];
    __shared__ u16 Bs[128][64];

    const int tid  = threadIdx.x;
    const int w    = tid >> 6;
    const int lane = tid & 63;
    const int lg   = lane >> 4;
    const int lr   = lane & 15;
    const int wr   = w >> 1, wc = w & 1;
    const int m0   = blockIdx.y * 128, n0 = blockIdx.x * 128;

    const f32x4 zero = {0.f, 0.f, 0.f, 0.f};
    f32x4 acc[4][4];
#pragma unroll
    for (int i = 0; i < 4; ++i)
#pragma unroll
        for (int j = 0; j < 4; ++j) acc[i][j] = zero;

    const int srow = tid >> 3;
    const int scol = (tid & 7) * 8;
    const int ldr  = w << 3;

    for (int k0 = 0; k0 < K; k0 += 64) {
        __syncthreads();
#pragma unroll
        for (int i = 0; i < 4; ++i) {
            const size_t ga = (size_t)(m0 + i * 32 + srow) * K + k0 + scol;
            const size_t gb = (size_t)(n0 + i * 32 + srow) * K + k0 + scol;
            gload16(&Ah[ga], &As[i * 32 + ldr][0]);
            gload16(&Bh[gb], &Bs[i * 32 + ldr][0]);
        }
        __syncthreads();
#pragma unroll
        for (int kk = 0; kk < 2; ++kk) {
            const int koff = kk * 32 + lg * 8;
#pragma unroll
            for (int mf = 0; mf < 4; ++mf) {
#pragma unroll
                for (int nf = 0; nf < 4; ++nf) {
                    if constexpr (FP16) {
                        const f16x8 a = *(const f16x8*)&As[wr * 64 + mf * 16 + lr][koff];
                        const f16x8 b = *(const f16x8*)&Bs[wc * 64 + nf * 16 + lr][koff];
                        acc[mf][nf] = __builtin_amdgcn_mfma_f32_16x16x32_f16(a, b, acc[mf][nf], 0, 0, 0);
                    } else {
                        const bf16x8 a = *(const bf16x8*)&As[wr * 64 + mf * 16 + lr][koff];
                        const bf16x8 b = *(const bf16x8*)&Bs[wc * 64 + nf * 16 + lr][koff];
                        acc[mf][nf] = __builtin_amdgcn_mfma_f32_16x16x32_bf16(a, b, acc[mf][nf], 0, 0, 0);
                    }
                }
            }
        }
    }

    // epilogue: C/D map col=lane&15, row=4*(lane>>4)+reg (verified)
#pragma unroll
    for (int mf = 0; mf < 4; ++mf)
#pragma unroll
        for (int nf = 0; nf < 4; ++nf)
#pragma unroll
            for (int j = 0; j < 4; ++j) {
                const int gm = m0 + wr * 64 + mf * 16 + lg * 4 + j;
                const int gn = n0 + wc * 64 + nf * 16 + lr;
                const float v = acc[mf][nf][j] + bias[gn];
                if constexpr (MODE == 0) {
                    const int bb = gm >> 10, t = gm & 1023;
                    const int c = gn >> 10, hh = (gn & 1023) >> 6, d = gn & 63;
                    const size_t idx = ((((size_t)bb * HH + hh) << 10) + t) * HDIM + d;
                    if (c == 0) dstH1[idx] = f2bf(v * 0.125f);       // q, pre-scaled
                    else        ((u16*)dstF)[idx] = f2bf(v);         // k bf16
                } else if constexpr (MODE == 1) {
                    const int bb = gm >> 10, t = gm & 1023;
                    const int hh = gn >> 6, d = gn & 63;
                    const size_t idx = ((((size_t)bb * HH + hh) << 10) + t) * HDIM + d;
                    dstH1[idx] = f2bf(v + bf2f(kaux16[idx]));        // kp = pk + k(bf16)
                } else {
                    dstF[(size_t)gm * N + gn] = v;
                }
            }
}

// ---------------------------------------------------------------------------
// MFMA attention v10: SINGLE-PASS, P in registers.
// Sweep 1 (kp staged dbuf): S = mfma(KP, Q) (swapped; lane's 16 values all
//   belong to q-row q0+w*16+lr), exp ONCE, rowsum per-lane, P packed bf16
//   into preg[16][8] (128 VGPRs, fully-static indexing).
// rowsum: 2x shfl_xor over lg bits -> ri; ri_s[w][16] for row-indexed use.
// Sweep 2 (kT staged in same LDS dbuf): per tile, preg -> P_s (4x
//   ds_write_b64), vectorized attn write (bf2f(P)*ri_row, f32x4 NT), PV
//   MFMA (unnormalized); ctx scaled by ri at end (linearity; r7 numerics).
// Frag maps verified: A/B row=lane&15, k=8*(lane>>4)+i; C/D col=lane&15,
// row=4*(lane>>4)+reg.
// ---------------------------------------------------------------------------
__global__ __launch_bounds__(256)
void attn_mfma(const u16* __restrict__ qg, const u16* __restrict__ kTg,
               const u16* __restrict__ kpg,
               float* __restrict__ attn, u16* __restrict__ ch)
{
    __shared__ u16 kv_s[2][64][72];   // kp (sweep1) then kT (sweep2), dbuf
    __shared__ u16 P_s[4][16][72];    // per-wave unnormalized P tile [q][kv]
    __shared__ float ri_s[4][16];

    const int tid  = threadIdx.x;
    const int w    = tid >> 6;        // wave 0..3
    const int lane = tid & 63;
    const int lg   = lane >> 4;       // 0..3
    const int lr   = lane & 15;       // 0..15

    // XCD swizzle (r12): fid -> (xcd c, slot s); head-group g = c + 8*(s>>4)
    const int fid = blockIdx.x;       // 0..1023
    const int c   = fid & 7;
    const int s   = fid >> 3;         // 0..127
    const int g   = c + 8 * (s >> 4); // 0..63
    const int q0  = (s & 15) * 64;
    const int b   = g >> 4, h = g & 15;
    const size_t hb = ((size_t)(b * HH + h)) << 16;    // head base (T*64 elems)

    // Q fragments (B operand of swapped QK^T): row lr -> q = q0 + w*16 + lr
    bf16x8 qf0, qf1;
    {
        const size_t base = hb + (size_t)(q0 + w * 16 + lr) * HDIM + lg * 8;
        qf0 = *(const bf16x8*)&qg[base];
        qf1 = *(const bf16x8*)&qg[base + 32];
    }

    const int sr = tid >> 2;          // staging row 0..63
    const int sc = (tid & 3) * 8;     // staging col chunk
    bf16x8 ra, rb;                    // staging registers

    // ---- sweep 1: swapped QK^T + exp -> preg, per-lane rowsum ----
    ra = *(const bf16x8*)&kpg[hb + (size_t)sr * HDIM + sc];
    rb = *(const bf16x8*)&kpg[hb + (size_t)sr * HDIM + sc + 32];
    *(bf16x8*)&kv_s[0][sr][sc]      = ra;
    *(bf16x8*)&kv_s[0][sr][sc + 32] = rb;
    __syncthreads();

    u32 preg[16][8];                  // 16 tiles x (4 ct x 2 packed-bf16)
    float rsum = 0.f;
#pragma unroll
    for (int t = 0; t < 16; ++t) {
        const int cur = t & 1;
        if (t < 15) {
            const size_t nb = hb + (size_t)((t + 1) * 64 + sr) * HDIM;
            ra = *(const bf16x8*)&kpg[nb + sc];
            rb = *(const bf16x8*)&kpg[nb + sc + 32];
        }
#pragma unroll
        for (int ct = 0; ct < 4; ++ct) {
            f32x4 acc = {0.f, 0.f, 0.f, 0.f};
            const bf16x8 a0 = *(const bf16x8*)&kv_s[cur][ct * 16 + lr][lg * 8];
            const bf16x8 a1 = *(const bf16x8*)&kv_s[cur][ct * 16 + lr][lg * 8 + 32];
            acc = __builtin_amdgcn_mfma_f32_16x16x32_bf16(a0, qf0, acc, 0, 0, 0);
            acc = __builtin_amdgcn_mfma_f32_16x16x32_bf16(a1, qf1, acc, 0, 0, 0);
            // lane: q = q0+w*16+lr, kv = t*64 + ct*16 + 4*lg + j
            const float p0 = __expf(acc[0]), p1 = __expf(acc[1]);
            const float p2 = __expf(acc[2]), p3 = __expf(acc[3]);
            rsum += (p0 + p1) + (p2 + p3);
            preg[t][ct * 2]     = (u32)f2bf(p0) | ((u32)f2bf(p1) << 16);
            preg[t][ct * 2 + 1] = (u32)f2bf(p2) | ((u32)f2bf(p3) << 16);
        }
        if (t < 15) {
            *(bf16x8*)&kv_s[cur ^ 1][sr][sc]      = ra;
            *(bf16x8*)&kv_s[cur ^ 1][sr][sc + 32] = rb;
        }
        __syncthreads();
    }

    // ---- rowsum reduce + sweep-2 prologue (kT tile0 loads overlap) ----
    ra = *(const bf16x8*)&kTg[hb + (size_t)sr * TT + sc];
    rb = *(const bf16x8*)&kTg[hb + (size_t)sr * TT + sc + 32];
    rsum += __shfl_xor(rsum, 16);
    rsum += __shfl_xor(rsum, 32);
    const float ri = 1.f / rsum;      // normalizer for q-row q0+w*16+lr
    if (lg == 0) ri_s[w][lr] = ri;
    *(bf16x8*)&kv_s[0][sr][sc]      = ra;
    *(bf16x8*)&kv_s[0][sr][sc + 32] = rb;
    __syncthreads();

    const int arow = lane >> 2;       // attn-write row 0..15
    const int acg  = lane & 3;        // attn-write col group
    const float ri_row = ri_s[w][arow];
    float ri_c[4];
#pragma unroll
    for (int j = 0; j < 4; ++j) ri_c[j] = ri_s[w][lg * 4 + j];

    // ---- sweep 2: P_s dump + attn write + PV ----
    f32x4 cacc[4] = {{0,0,0,0},{0,0,0,0},{0,0,0,0},{0,0,0,0}};
    const size_t abase = ((((size_t)b * HH + h) << 10) + q0 + w * 16) << 10;

#pragma unroll
    for (int t = 0; t < 16; ++t) {
        const int cur = t & 1;
        if (t < 15) {
            const size_t tb = hb + (size_t)sr * TT + (t + 1) * 64;
            ra = *(const bf16x8*)&kTg[tb + sc];
            rb = *(const bf16x8*)&kTg[tb + sc + 32];
        }
        // preg[t] -> P_s (wave-local; kv = ct*16 + 4*lg + j for q-row lr)
#pragma unroll
        for (int ct = 0; ct < 4; ++ct) {
            u32x2 pw = {preg[t][ct * 2], preg[t][ct * 2 + 1]};
            *(u32x2*)&P_s[w][lr][ct * 16 + lg * 4] = pw;
        }
        asm volatile("s_waitcnt lgkmcnt(0)" ::: "memory");   // P_s w->r, same wave
        // attn write: unnormalized bf16 tile * ri_row -> f32x4 NT stores
        {
            float* wbase = &attn[abase + (size_t)arow * TT + t * 64 + acg * 4];
#pragma unroll
            for (int kq = 0; kq < 4; ++kq) {
                const u16x4 pv = *(const u16x4*)&P_s[w][arow][kq * 16 + acg * 4];
                f32x4 o = {bf2f(pv[0]) * ri_row, bf2f(pv[1]) * ri_row,
                           bf2f(pv[2]) * ri_row, bf2f(pv[3]) * ri_row};
                __builtin_nontemporal_store(o, (f32x4*)(wbase + kq * 16));
            }
        }
        // PV: A = P_s rows (q-row lr), B = kT rows (d = dt*16+lr)
        const bf16x8 pa0 = *(const bf16x8*)&P_s[w][lr][lg * 8];
        const bf16x8 pa1 = *(const bf16x8*)&P_s[w][lr][lg * 8 + 32];
#pragma unroll
        for (int dt = 0; dt < 4; ++dt) {
            const bf16x8 kb0 = *(const bf16x8*)&kv_s[cur][dt * 16 + lr][lg * 8];
            const bf16x8 kb1 = *(const bf16x8*)&kv_s[cur][dt * 16 + lr][lg * 8 + 32];
            cacc[dt] = __builtin_amdgcn_mfma_f32_16x16x32_bf16(pa0, kb0, cacc[dt], 0, 0, 0);
            cacc[dt] = __builtin_amdgcn_mfma_f32_16x16x32_bf16(pa1, kb1, cacc[dt], 0, 0, 0);
        }
        if (t < 15) {
            *(bf16x8*)&kv_s[cur ^ 1][sr][sc]      = ra;
            *(bf16x8*)&kv_s[cur ^ 1][sr][sc + 32] = rb;
        }
        __syncthreads();
    }

    // ctx -> bf16 [B][T][H*64]; C/D: q-row = lg*4+j, d = dt*16+lr
#pragma unroll
    for (int dt = 0; dt < 4; ++dt)
#pragma unroll
        for (int j = 0; j < 4; ++j) {
            const int qr = q0 + w * 16 + lg * 4 + j;
            ch[(((size_t)b << 10) + qr) * DD + h * HDIM + dt * 16 + lr] =
                f2bf(cacc[dt][j] * ri_c[j]);
        }
}

extern "C" void kernel_launch(void* const* d_in, const int* in_sizes, int n_in,
                              void* d_out, int out_size, void* d_ws, size_t ws_size,
                              hipStream_t stream)
{
    const float* x  = (const float*)d_in[0];
    const float* pe = (const float*)d_in[1];
    const float* Wc = (const float*)d_in[2];
    const float* bc = (const float*)d_in[3];
    const float* Wp = (const float*)d_in[4];
    const float* bp = (const float*)d_in[5];
    const float* Wo = (const float*)d_in[6];
    const float* bo = (const float*)d_in[7];

    float* out  = (float*)d_out;                         // [B][T][D]
    float* attn = out + (size_t)MM * DD;                 // [B][H][T][T]

    // 64 MB workspace layout -- fully disjoint regions (chh reuses x16
    // after cqk; everything else has its own home):
    char* ws = (char*)d_ws;
    u16* x16  = (u16*)(ws);                              // [0,8M)    fp16; -> chh after cqk
    u16* pe16 = (u16*)(ws + ((size_t)8 << 20));          // [8,16M)   fp16
    u16* Wc16 = (u16*)(ws + ((size_t)16 << 20));         // [16,20M)  fp16
    u16* Wp16 = (u16*)(ws + ((size_t)20 << 20));         // [20,22M)  fp16
    u16* Wo16 = (u16*)(ws + ((size_t)22 << 20));         // [22,24M)  bf16
    u16* q16  = (u16*)(ws + ((size_t)24 << 20));         // [24,32M)  bf16
    u16* k16  = (u16*)(ws + ((size_t)32 << 20));         // [32,40M)  bf16
    u16* kp16 = (u16*)(ws + ((size_t)40 << 20));         // [40,48M)  bf16
    u16* k16T = (u16*)(ws + ((size_t)56 << 20));         // [56,64M)  bf16
    u16* chh  = x16;                                     // ctx bf16 (x dead after cqk)

    // 1) all input conversions, one launch
    cvt_all_kernel<<<12288, 256, 0, stream>>>(x, x16, pe, pe16, Wc, Wc16,
                                              Wp, Wp16, Wo, Wo16);
    // 2) cqk = x @ Wc^T + bc  (fp16 MFMA) -> q16 (scaled bf16), k16 (bf16)
    gemm_mfma<true, 0><<<dim3(16, 32), 256, 0, stream>>>(
        x16, Wc16, bc, (float*)k16, q16, nullptr, MM, 2048, DD);
    // 3) k16T = transpose(k16)
    ktrans_kernel<<<dim3(16, HH, BB), 256, 0, stream>>>(k16, k16T);
    // 4) pk = pe @ Wp^T + bp (fp16 MFMA); kp16 = bf16(pk + k16)
    gemm_mfma<true, 1><<<dim3(8, 32), 256, 0, stream>>>(
        pe16, Wp16, bp, nullptr, kp16, k16, MM, 1024, DD);
    // 5) attention: single-pass, P in registers
    attn_mfma<<<1024, 256, 0, stream>>>(q16, k16T, kp16, attn, chh);
    // 6) out = ctx @ Wo^T + bo (bf16 MFMA)
    gemm_mfma<false, 2><<<dim3(8, 32), 256, 0, stream>>>(
        chh, Wo16, bo, out, nullptr, nullptr, MM, 1024, DD);
}

// Round 17
// 183.152 us; speedup vs baseline: 1.1577x; 1.1577x over previous
//
#include <hip/hip_runtime.h>
#include <hip/hip_bf16.h>

// Problem constants (fixed by the reference)
#define BB 4
#define TT 1024
#define DD 1024
#define HH 16
#define HDIM 64
#define MM (BB*TT)          // 4096

typedef unsigned short u16;
typedef __attribute__((ext_vector_type(8))) short bf16x8;     // 8 bf16 = 4 VGPRs
typedef __attribute__((ext_vector_type(8))) _Float16 f16x8;   // 8 fp16 = 4 VGPRs
typedef __attribute__((ext_vector_type(4))) float f32x4;
typedef __attribute__((ext_vector_type(4))) unsigned short u16x4;

__device__ __forceinline__ u16 f2bf(float f) {
    union { float f; unsigned u; } v; v.f = f;
    return (u16)((v.u + 0x7fffu + ((v.u >> 16) & 1u)) >> 16);   // RNE
}
__device__ __forceinline__ float bf2f(u16 h) {
    union { unsigned u; float f; } v; v.u = ((unsigned)h) << 16; return v.f;
}
__device__ __forceinline__ u16 f2h(float f) {
    union { _Float16 h; u16 u; } v; v.h = (_Float16)f;          // v_cvt_f16_f32 RNE
    return v.u;
}

// async global->LDS, 16B per lane; lds dest = wave-uniform base + lane*16
__device__ __forceinline__ void gload16(const void* g, void* l) {
    __builtin_amdgcn_global_load_lds(
        (const __attribute__((address_space(1))) unsigned int*)g,
        (__attribute__((address_space(3))) unsigned int*)l, 16, 0, 0);
}

__device__ __forceinline__ void cvt_body(const float* __restrict__ src,
                                         u16* __restrict__ dst,
                                         int bid, bool to_fp16)
{
    const size_t i = ((size_t)bid * 256 + threadIdx.x) * 4;
    const float4 v = *(const float4*)&src[i];
    u16x4 o;
    if (to_fp16) { o[0] = f2h(v.x); o[1] = f2h(v.y); o[2] = f2h(v.z); o[3] = f2h(v.w); }
    else         { o[0] = f2bf(v.x); o[1] = f2bf(v.y); o[2] = f2bf(v.z); o[3] = f2bf(v.w); }
    *(u16x4*)&dst[i] = o;
}

// single fused conversion kernel: x,pe,Wc,Wp -> fp16; Wo -> bf16
__global__ __launch_bounds__(256)
void cvt_all_kernel(const float* __restrict__ x,  u16* __restrict__ x16,
                    const float* __restrict__ pe, u16* __restrict__ pe16,
                    const float* __restrict__ Wc, u16* __restrict__ Wc16,
                    const float* __restrict__ Wp, u16* __restrict__ Wp16,
                    const float* __restrict__ Wo, u16* __restrict__ Wo16)
{
    const int bid = blockIdx.x;
    if (bid < 4096)       cvt_body(x,  x16,  bid,        true);
    else if (bid < 8192)  cvt_body(pe, pe16, bid - 4096, true);
    else if (bid < 10240) cvt_body(Wc, Wc16, bid - 8192, true);
    else if (bid < 11264) cvt_body(Wp, Wp16, bid - 10240, true);
    else                  cvt_body(Wo, Wo16, bid - 11264, false);
}

// ---------------------------------------------------------------------------
// MFMA GEMM: C = A @ B^T + bias (r12 structure).
// MODE 0 (cqk, N=2048): n<1024 -> q16 = bf16(v*0.125); else k16 = bf16(v)
// MODE 2 (out):         dstF row-major f32
// ---------------------------------------------------------------------------
template<bool FP16, int MODE>
__global__ __launch_bounds__(256)
void gemm_mfma(const u16* __restrict__ Ah, const u16* __restrict__ Bh,
               const float* __restrict__ bias,
               float* __restrict__ dstF, u16* __restrict__ dstH1,
               const u16* __restrict__ kaux16,
               const int M, const int N, const int K)
{
    __shared__ u16 As[128][64];
    __shared__ u16 Bs[128][64];

    const int tid  = threadIdx.x;
    const int w    = tid >> 6;
    const int lane = tid & 63;
    const int lg   = lane >> 4;
    const int lr   = lane & 15;
    const int wr   = w >> 1, wc = w & 1;
    const int m0   = blockIdx.y * 128, n0 = blockIdx.x * 128;

    const f32x4 zero = {0.f, 0.f, 0.f, 0.f};
    f32x4 acc[4][4];
#pragma unroll
    for (int i = 0; i < 4; ++i)
#pragma unroll
        for (int j = 0; j < 4; ++j) acc[i][j] = zero;

    const int srow = tid >> 3;
    const int scol = (tid & 7) * 8;
    const int ldr  = w << 3;

    for (int k0 = 0; k0 < K; k0 += 64) {
        __syncthreads();
#pragma unroll
        for (int i = 0; i < 4; ++i) {
            const size_t ga = (size_t)(m0 + i * 32 + srow) * K + k0 + scol;
            const size_t gb = (size_t)(n0 + i * 32 + srow) * K + k0 + scol;
            gload16(&Ah[ga], &As[i * 32 + ldr][0]);
            gload16(&Bh[gb], &Bs[i * 32 + ldr][0]);
        }
        __syncthreads();
#pragma unroll
        for (int kk = 0; kk < 2; ++kk) {
            const int koff = kk * 32 + lg * 8;
#pragma unroll
            for (int mf = 0; mf < 4; ++mf) {
#pragma unroll
                for (int nf = 0; nf < 4; ++nf) {
                    if constexpr (FP16) {
                        const f16x8 a = *(const f16x8*)&As[wr * 64 + mf * 16 + lr][koff];
                        const f16x8 b = *(const f16x8*)&Bs[wc * 64 + nf * 16 + lr][koff];
                        acc[mf][nf] = __builtin_amdgcn_mfma_f32_16x16x32_f16(a, b, acc[mf][nf], 0, 0, 0);
                    } else {
                        const bf16x8 a = *(const bf16x8*)&As[wr * 64 + mf * 16 + lr][koff];
                        const bf16x8 b = *(const bf16x8*)&Bs[wc * 64 + nf * 16 + lr][koff];
                        acc[mf][nf] = __builtin_amdgcn_mfma_f32_16x16x32_bf16(a, b, acc[mf][nf], 0, 0, 0);
                    }
                }
            }
        }
    }

    // epilogue: C/D map col=lane&15, row=4*(lane>>4)+reg (verified)
#pragma unroll
    for (int mf = 0; mf < 4; ++mf)
#pragma unroll
        for (int nf = 0; nf < 4; ++nf)
#pragma unroll
            for (int j = 0; j < 4; ++j) {
                const int gm = m0 + wr * 64 + mf * 16 + lg * 4 + j;
                const int gn = n0 + wc * 64 + nf * 16 + lr;
                const float v = acc[mf][nf][j] + bias[gn];
                if constexpr (MODE == 0) {
                    const int bb = gm >> 10, t = gm & 1023;
                    const int c = gn >> 10, hh = (gn & 1023) >> 6, d = gn & 63;
                    const size_t idx = ((((size_t)bb * HH + hh) << 10) + t) * HDIM + d;
                    if (c == 0) dstH1[idx] = f2bf(v * 0.125f);       // q, pre-scaled
                    else        ((u16*)dstF)[idx] = f2bf(v);         // k bf16
                } else {
                    dstF[(size_t)gm * N + gn] = v;
                }
            }
}

// ---------------------------------------------------------------------------
// Fused pk-GEMM + ktrans. Blocks [0,256): pk = pe @ Wp^T + bp (fp16 MFMA),
// kp16 = bf16(pk + k16). Blocks [256,1280): k16 -> k16T per-head transpose.
// The two parts are independent (both consume cqk outputs); merging lets the
// 1024 tiny transpose blocks co-schedule on the CUs left idle by the
// 1-block/CU GEMM part and removes one launch gap. LDS overlaid (32 KB).
// ---------------------------------------------------------------------------
__global__ __launch_bounds__(256)
void pk_fused_kernel(const u16* __restrict__ Ah, const u16* __restrict__ Bh,
                     const float* __restrict__ bias,
                     u16* __restrict__ kp16, const u16* __restrict__ kaux16,
                     u16* __restrict__ k16T)
{
    __shared__ __align__(16) u16 smem[2 * 128 * 64];   // 32 KB, both paths
    const int tid = threadIdx.x;

    if (blockIdx.x >= 256) {
        // ---- ktrans path ----
        auto tmp = (u16(*)[72])smem;                   // [64][72] = 9 KB
        const int bid = blockIdx.x - 256;
        const int tc = bid & 15, h = (bid >> 4) & 15, b = bid >> 8;
        const size_t hb = ((size_t)(b * HH + h)) << 16;
        const int sr = tid >> 2, sc = (tid & 3) * 8;
        *(bf16x8*)&tmp[sr][sc]      = *(const bf16x8*)&kaux16[hb + (size_t)(tc * 64 + sr) * HDIM + sc];
        *(bf16x8*)&tmp[sr][sc + 32] = *(const bf16x8*)&kaux16[hb + (size_t)(tc * 64 + sr) * HDIM + sc + 32];
        __syncthreads();
#pragma unroll
        for (int half = 0; half < 2; ++half) {
            bf16x8 v;
#pragma unroll
            for (int j = 0; j < 8; ++j) v[j] = (short)tmp[sc + half * 32 + j][sr];
            *(bf16x8*)&k16T[hb + (size_t)sr * TT + tc * 64 + sc + half * 32] = v;
        }
        return;
    }

    // ---- pk GEMM path (fp16, MODE-1 epilogue) ----
    auto As = (u16(*)[64])smem;
    auto Bs = (u16(*)[64])(smem + 128 * 64);
    const int w    = tid >> 6;
    const int lane = tid & 63;
    const int lg   = lane >> 4;
    const int lr   = lane & 15;
    const int wr   = w >> 1, wc = w & 1;
    const int m0   = (blockIdx.x >> 3) * 128, n0 = (blockIdx.x & 7) * 128;
    const int K = DD;

    const f32x4 zero = {0.f, 0.f, 0.f, 0.f};
    f32x4 acc[4][4];
#pragma unroll
    for (int i = 0; i < 4; ++i)
#pragma unroll
        for (int j = 0; j < 4; ++j) acc[i][j] = zero;

    const int srow = tid >> 3;
    const int scol = (tid & 7) * 8;
    const int ldr  = w << 3;

    for (int k0 = 0; k0 < K; k0 += 64) {
        __syncthreads();
#pragma unroll
        for (int i = 0; i < 4; ++i) {
            const size_t ga = (size_t)(m0 + i * 32 + srow) * K + k0 + scol;
            const size_t gb = (size_t)(n0 + i * 32 + srow) * K + k0 + scol;
            gload16(&Ah[ga], &As[i * 32 + ldr][0]);
            gload16(&Bh[gb], &Bs[i * 32 + ldr][0]);
        }
        __syncthreads();
#pragma unroll
        for (int kk = 0; kk < 2; ++kk) {
            const int koff = kk * 32 + lg * 8;
#pragma unroll
            for (int mf = 0; mf < 4; ++mf) {
#pragma unroll
                for (int nf = 0; nf < 4; ++nf) {
                    const f16x8 a = *(const f16x8*)&As[wr * 64 + mf * 16 + lr][koff];
                    const f16x8 b = *(const f16x8*)&Bs[wc * 64 + nf * 16 + lr][koff];
                    acc[mf][nf] = __builtin_amdgcn_mfma_f32_16x16x32_f16(a, b, acc[mf][nf], 0, 0, 0);
                }
            }
        }
    }

#pragma unroll
    for (int mf = 0; mf < 4; ++mf)
#pragma unroll
        for (int nf = 0; nf < 4; ++nf)
#pragma unroll
            for (int j = 0; j < 4; ++j) {
                const int gm = m0 + wr * 64 + mf * 16 + lg * 4 + j;
                const int gn = n0 + wc * 64 + nf * 16 + lr;
                const float v = acc[mf][nf][j] + bias[gn];
                const int bb = gm >> 10, t = gm & 1023;
                const int hh = gn >> 6, d = gn & 63;
                const size_t idx = ((((size_t)bb * HH + hh) << 10) + t) * HDIM + d;
                kp16[idx] = f2bf(v + bf2f(kaux16[idx]));             // kp = pk + k(bf16)
            }
}

// ---------------------------------------------------------------------------
// MFMA attention v9 (r15, measured best): 4 waves, QBLK=64, dbuf staging,
// XCD head-group swizzle, vectorized f32x4 NT attn write from wave-local
// bf16 P tile. No setprio (r14: -9us on lockstep). Two-pass recompute (every
// single-exp variant measured worse: r5/r6/r7/r16).
// ---------------------------------------------------------------------------
__global__ __launch_bounds__(256)
void attn_mfma(const u16* __restrict__ qg, const u16* __restrict__ kTg,
               const u16* __restrict__ kpg,
               float* __restrict__ attn, u16* __restrict__ ch)
{
    __shared__ u16 kp_s[2][64][72];   // kp tiles, double-buffered
    __shared__ u16 kT_s[2][64][72];   // kT tiles, double-buffered
    __shared__ u16 P_s[4][16][72];    // per-wave normalized P tile [q][kk]

    const int tid  = threadIdx.x;
    const int w    = tid >> 6;        // wave 0..3
    const int lane = tid & 63;
    const int lg   = lane >> 4;       // 0..3
    const int lr   = lane & 15;       // 0..15

    // XCD swizzle: fid -> (xcd c, slot s); head-group g = c + 8*(s>>4)
    const int fid = blockIdx.x;       // 0..1023
    const int c   = fid & 7;
    const int s   = fid >> 3;         // 0..127
    const int g   = c + 8 * (s >> 4); // 0..63
    const int q0  = (s & 15) * 64;
    const int b   = g >> 4, h = g & 15;
    const size_t hb = ((size_t)(b * HH + h)) << 16;    // head base (T*64 elems)

    bf16x8 qf0, qf1;
    {
        const size_t base = hb + (size_t)(q0 + w * 16 + lr) * HDIM + lg * 8;
        qf0 = *(const bf16x8*)&qg[base];
        qf1 = *(const bf16x8*)&qg[base + 32];
    }

    const int sr = tid >> 2;          // staging row 0..63
    const int sc = (tid & 3) * 8;     // staging col chunk
    bf16x8 ra, rb, rc, rd;            // staging registers

    // ---- pass 1: rowsums ----
    ra = *(const bf16x8*)&kpg[hb + (size_t)sr * HDIM + sc];
    rb = *(const bf16x8*)&kpg[hb + (size_t)sr * HDIM + sc + 32];
    *(bf16x8*)&kp_s[0][sr][sc]      = ra;
    *(bf16x8*)&kp_s[0][sr][sc + 32] = rb;
    __syncthreads();

    float rs[4] = {0.f, 0.f, 0.f, 0.f};
    for (int t = 0; t < TT / 64; ++t) {
        const int cur = t & 1;
        if (t < 15) {   // prefetch next tile into regs
            const size_t nb = hb + (size_t)((t + 1) * 64 + sr) * HDIM;
            ra = *(const bf16x8*)&kpg[nb + sc];
            rb = *(const bf16x8*)&kpg[nb + sc + 32];
        }
#pragma unroll
        for (int ct = 0; ct < 4; ++ct) {
            f32x4 acc = {0.f, 0.f, 0.f, 0.f};
            const bf16x8 b0 = *(const bf16x8*)&kp_s[cur][ct * 16 + lr][lg * 8];
            const bf16x8 b1 = *(const bf16x8*)&kp_s[cur][ct * 16 + lr][lg * 8 + 32];
            acc = __builtin_amdgcn_mfma_f32_16x16x32_bf16(qf0, b0, acc, 0, 0, 0);
            acc = __builtin_amdgcn_mfma_f32_16x16x32_bf16(qf1, b1, acc, 0, 0, 0);
#pragma unroll
            for (int j = 0; j < 4; ++j) rs[j] += __expf(acc[j]);
        }
        if (t < 15) {   // implicit vmcnt wait on ra/rb; write other buffer
            *(bf16x8*)&kp_s[cur ^ 1][sr][sc]      = ra;
            *(bf16x8*)&kp_s[cur ^ 1][sr][sc + 32] = rb;
        }
        __syncthreads();
    }

    // ---- rowsum reduce + pass-2 prologue (loads overlap the reduce) ----
    ra = *(const bf16x8*)&kpg[hb + (size_t)sr * HDIM + sc];
    rb = *(const bf16x8*)&kpg[hb + (size_t)sr * HDIM + sc + 32];
    rc = *(const bf16x8*)&kTg[hb + (size_t)sr * TT + sc];
    rd = *(const bf16x8*)&kTg[hb + (size_t)sr * TT + sc + 32];
#pragma unroll
    for (int off = 1; off < 16; off <<= 1) {
#pragma unroll
        for (int j = 0; j < 4; ++j) rs[j] += __shfl_xor(rs[j], off);
    }
    float ri[4];
#pragma unroll
    for (int j = 0; j < 4; ++j) ri[j] = 1.f / rs[j];
    *(bf16x8*)&kp_s[0][sr][sc]      = ra;
    *(bf16x8*)&kp_s[0][sr][sc + 32] = rb;
    *(bf16x8*)&kT_s[0][sr][sc]      = rc;
    *(bf16x8*)&kT_s[0][sr][sc + 32] = rd;
    __syncthreads();

    // ---- pass 2: P tile + vectorized attn write + PV ----
    f32x4 cacc[4] = {{0,0,0,0},{0,0,0,0},{0,0,0,0},{0,0,0,0}};
    const size_t abase = ((((size_t)b * HH + h) << 10) + q0 + w * 16) << 10;
    const int arow = lane >> 2;       // attn-write row 0..15
    const int acg  = lane & 3;        // attn-write col group

    for (int t = 0; t < TT / 64; ++t) {
        const int cur = t & 1;
        if (t < 15) {   // prefetch next kp + kT tiles into regs
            const size_t nb = hb + (size_t)((t + 1) * 64 + sr) * HDIM;
            ra = *(const bf16x8*)&kpg[nb + sc];
            rb = *(const bf16x8*)&kpg[nb + sc + 32];
            const size_t tb = hb + (size_t)sr * TT + (t + 1) * 64;
            rc = *(const bf16x8*)&kTg[tb + sc];
            rd = *(const bf16x8*)&kTg[tb + sc + 32];
        }
#pragma unroll
        for (int ct = 0; ct < 4; ++ct) {
            f32x4 acc = {0.f, 0.f, 0.f, 0.f};
            const bf16x8 b0 = *(const bf16x8*)&kp_s[cur][ct * 16 + lr][lg * 8];
            const bf16x8 b1 = *(const bf16x8*)&kp_s[cur][ct * 16 + lr][lg * 8 + 32];
            acc = __builtin_amdgcn_mfma_f32_16x16x32_bf16(qf0, b0, acc, 0, 0, 0);
            acc = __builtin_amdgcn_mfma_f32_16x16x32_bf16(qf1, b1, acc, 0, 0, 0);
#pragma unroll
            for (int j = 0; j < 4; ++j) {
                const float p = __expf(acc[j]) * ri[j];
                P_s[w][lg * 4 + j][ct * 16 + lr] = f2bf(p);
            }
        }
        asm volatile("s_waitcnt lgkmcnt(0)" ::: "memory");   // P_s write->read, same wave
        // attn write: wave-local normalized bf16 tile -> f32x4 NT stores
        {
            float* wbase = &attn[abase + (size_t)arow * TT + t * 64 + acg * 4];
#pragma unroll
            for (int kq = 0; kq < 4; ++kq) {
                const u16x4 pv = *(const u16x4*)&P_s[w][arow][kq * 16 + acg * 4];
                f32x4 o = {bf2f(pv[0]), bf2f(pv[1]), bf2f(pv[2]), bf2f(pv[3])};
                __builtin_nontemporal_store(o, (f32x4*)(wbase + kq * 16));
            }
        }
        const bf16x8 pa0 = *(const bf16x8*)&P_s[w][lr][lg * 8];
        const bf16x8 pa1 = *(const bf16x8*)&P_s[w][lr][lg * 8 + 32];
#pragma unroll
        for (int dt = 0; dt < 4; ++dt) {
            const bf16x8 kb0 = *(const bf16x8*)&kT_s[cur][dt * 16 + lr][lg * 8];
            const bf16x8 kb1 = *(const bf16x8*)&kT_s[cur][dt * 16 + lr][lg * 8 + 32];
            cacc[dt] = __builtin_amdgcn_mfma_f32_16x16x32_bf16(pa0, kb0, cacc[dt], 0, 0, 0);
            cacc[dt] = __builtin_amdgcn_mfma_f32_16x16x32_bf16(pa1, kb1, cacc[dt], 0, 0, 0);
        }
        if (t < 15) {
            *(bf16x8*)&kp_s[cur ^ 1][sr][sc]      = ra;
            *(bf16x8*)&kp_s[cur ^ 1][sr][sc + 32] = rb;
            *(bf16x8*)&kT_s[cur ^ 1][sr][sc]      = rc;
            *(bf16x8*)&kT_s[cur ^ 1][sr][sc + 32] = rd;
        }
        __syncthreads();
    }

    // ctx -> bf16 [B][T][H*64]
#pragma unroll
    for (int dt = 0; dt < 4; ++dt)
#pragma unroll
        for (int j = 0; j < 4; ++j) {
            const int qr = q0 + w * 16 + lg * 4 + j;
            ch[(((size_t)b << 10) + qr) * DD + h * HDIM + dt * 16 + lr] = f2bf(cacc[dt][j]);
        }
}

extern "C" void kernel_launch(void* const* d_in, const int* in_sizes, int n_in,
                              void* d_out, int out_size, void* d_ws, size_t ws_size,
                              hipStream_t stream)
{
    const float* x  = (const float*)d_in[0];
    const float* pe = (const float*)d_in[1];
    const float* Wc = (const float*)d_in[2];
    const float* bc = (const float*)d_in[3];
    const float* Wp = (const float*)d_in[4];
    const float* bp = (const float*)d_in[5];
    const float* Wo = (const float*)d_in[6];
    const float* bo = (const float*)d_in[7];

    float* out  = (float*)d_out;                         // [B][T][D]
    float* attn = out + (size_t)MM * DD;                 // [B][H][T][T]

    // 64 MB workspace layout -- fully disjoint regions (chh reuses x16
    // after cqk; everything else has its own home):
    char* ws = (char*)d_ws;
    u16* x16  = (u16*)(ws);                              // [0,8M)    fp16; -> chh after cqk
    u16* pe16 = (u16*)(ws + ((size_t)8 << 20));          // [8,16M)   fp16
    u16* Wc16 = (u16*)(ws + ((size_t)16 << 20));         // [16,20M)  fp16
    u16* Wp16 = (u16*)(ws + ((size_t)20 << 20));         // [20,22M)  fp16
    u16* Wo16 = (u16*)(ws + ((size_t)22 << 20));         // [22,24M)  bf16
    u16* q16  = (u16*)(ws + ((size_t)24 << 20));         // [24,32M)  bf16
    u16* k16  = (u16*)(ws + ((size_t)32 << 20));         // [32,40M)  bf16
    u16* kp16 = (u16*)(ws + ((size_t)40 << 20));         // [40,48M)  bf16
    u16* k16T = (u16*)(ws + ((size_t)56 << 20));         // [56,64M)  bf16
    u16* chh  = x16;                                     // ctx bf16 (x dead after cqk)

    // 1) all input conversions, one launch
    cvt_all_kernel<<<12288, 256, 0, stream>>>(x, x16, pe, pe16, Wc, Wc16,
                                              Wp, Wp16, Wo, Wo16);
    // 2) cqk = x @ Wc^T + bc  (fp16 MFMA) -> q16 (scaled bf16), k16 (bf16)
    gemm_mfma<true, 0><<<dim3(16, 32), 256, 0, stream>>>(
        x16, Wc16, bc, (float*)k16, q16, nullptr, MM, 2048, DD);
    // 3) fused: pk GEMM (kp16 = bf16(pk + k16)) + ktrans (k16 -> k16T)
    pk_fused_kernel<<<1280, 256, 0, stream>>>(
        pe16, Wp16, bp, kp16, k16, k16T);
    // 4) attention: attn f32 + ctx bf16 (r15 structure)
    attn_mfma<<<1024, 256, 0, stream>>>(q16, k16T, kp16, attn, chh);
    // 5) out = ctx @ Wo^T + bo (bf16 MFMA)
    gemm_mfma<false, 2><<<dim3(8, 32), 256, 0, stream>>>(
        chh, Wo16, bo, out, nullptr, nullptr, MM, 1024, DD);
}

// Round 18
// 181.903 us; speedup vs baseline: 1.1657x; 1.0069x over previous
//
#include <hip/hip_runtime.h>
#include <hip/hip_bf16.h>

// Problem constants (fixed by the reference)
#define BB 4
#define TT 1024
#define DD 1024
#define HH 16
#define HDIM 64
#define MM (BB*TT)          // 4096

typedef unsigned short u16;
typedef __attribute__((ext_vector_type(8))) short bf16x8;     // 8 bf16 = 4 VGPRs
typedef __attribute__((ext_vector_type(8))) _Float16 f16x8;   // 8 fp16 = 4 VGPRs
typedef __attribute__((ext_vector_type(4))) float f32x4;
typedef __attribute__((ext_vector_type(4))) unsigned short u16x4;

__device__ __forceinline__ u16 f2bf(float f) {
    union { float f; unsigned u; } v; v.f = f;
    return (u16)((v.u + 0x7fffu + ((v.u >> 16) & 1u)) >> 16);   // RNE
}
__device__ __forceinline__ float bf2f(u16 h) {
    union { unsigned u; float f; } v; v.u = ((unsigned)h) << 16; return v.f;
}
__device__ __forceinline__ u16 f2h(float f) {
    union { _Float16 h; u16 u; } v; v.h = (_Float16)f;          // v_cvt_f16_f32 RNE
    return v.u;
}

// async global->LDS, 16B per lane; lds dest = wave-uniform base + lane*16
__device__ __forceinline__ void gload16(const void* g, void* l) {
    __builtin_amdgcn_global_load_lds(
        (const __attribute__((address_space(1))) unsigned int*)g,
        (__attribute__((address_space(3))) unsigned int*)l, 16, 0, 0);
}

__device__ __forceinline__ void cvt_body(const float* __restrict__ src,
                                         u16* __restrict__ dst,
                                         int bid, bool to_fp16)
{
    const size_t i = ((size_t)bid * 256 + threadIdx.x) * 4;
    const float4 v = *(const float4*)&src[i];
    u16x4 o;
    if (to_fp16) { o[0] = f2h(v.x); o[1] = f2h(v.y); o[2] = f2h(v.z); o[3] = f2h(v.w); }
    else         { o[0] = f2bf(v.x); o[1] = f2bf(v.y); o[2] = f2bf(v.z); o[3] = f2bf(v.w); }
    *(u16x4*)&dst[i] = o;
}

// single fused conversion kernel: x,pe,Wc,Wp -> fp16; Wo -> bf16
__global__ __launch_bounds__(256)
void cvt_all_kernel(const float* __restrict__ x,  u16* __restrict__ x16,
                    const float* __restrict__ pe, u16* __restrict__ pe16,
                    const float* __restrict__ Wc, u16* __restrict__ Wc16,
                    const float* __restrict__ Wp, u16* __restrict__ Wp16,
                    const float* __restrict__ Wo, u16* __restrict__ Wo16)
{
    const int bid = blockIdx.x;
    if (bid < 4096)       cvt_body(x,  x16,  bid,        true);
    else if (bid < 8192)  cvt_body(pe, pe16, bid - 4096, true);
    else if (bid < 10240) cvt_body(Wc, Wc16, bid - 8192, true);
    else if (bid < 11264) cvt_body(Wp, Wp16, bid - 10240, true);
    else                  cvt_body(Wo, Wo16, bid - 11264, false);
}

// ---------------------------------------------------------------------------
// MFMA GEMM: C = A @ B^T + bias (r12 structure) + XCD-chunk swizzle.
// 1D grid, nwg divisible by 8. wg = (fid&7)<<CPXSH | fid>>3 gives each XCD a
// contiguous chunk of m-panels -> A-panels fetched once per XCD, B sub-panels
// get temporal reuse within the XCD's private L2.
// MODE 0 (cqk, N=2048): n<1024 -> q16 = bf16(v*0.125); else k16 = bf16(v)
// MODE 2 (out):         dstF row-major f32
// ---------------------------------------------------------------------------
template<bool FP16, int MODE, int NNSH, int CPXSH>
__global__ __launch_bounds__(256)
void gemm_mfma(const u16* __restrict__ Ah, const u16* __restrict__ Bh,
               const float* __restrict__ bias,
               float* __restrict__ dstF, u16* __restrict__ dstH1,
               const u16* __restrict__ kaux16,
               const int M, const int N, const int K)
{
    __shared__ u16 As[128][64];
    __shared__ u16 Bs[128][64];

    const int tid  = threadIdx.x;
    const int w    = tid >> 6;
    const int lane = tid & 63;
    const int lg   = lane >> 4;
    const int lr   = lane & 15;
    const int wr   = w >> 1, wc = w & 1;
    const int fid  = blockIdx.x;
    const int wg   = ((fid & 7) << CPXSH) | (fid >> 3);
    const int m0   = (wg >> NNSH) * 128;
    const int n0   = (wg & ((1 << NNSH) - 1)) * 128;

    const f32x4 zero = {0.f, 0.f, 0.f, 0.f};
    f32x4 acc[4][4];
#pragma unroll
    for (int i = 0; i < 4; ++i)
#pragma unroll
        for (int j = 0; j < 4; ++j) acc[i][j] = zero;

    const int srow = tid >> 3;
    const int scol = (tid & 7) * 8;
    const int ldr  = w << 3;

    for (int k0 = 0; k0 < K; k0 += 64) {
        __syncthreads();
#pragma unroll
        for (int i = 0; i < 4; ++i) {
            const size_t ga = (size_t)(m0 + i * 32 + srow) * K + k0 + scol;
            const size_t gb = (size_t)(n0 + i * 32 + srow) * K + k0 + scol;
            gload16(&Ah[ga], &As[i * 32 + ldr][0]);
            gload16(&Bh[gb], &Bs[i * 32 + ldr][0]);
        }
        __syncthreads();
#pragma unroll
        for (int kk = 0; kk < 2; ++kk) {
            const int koff = kk * 32 + lg * 8;
#pragma unroll
            for (int mf = 0; mf < 4; ++mf) {
#pragma unroll
                for (int nf = 0; nf < 4; ++nf) {
                    if constexpr (FP16) {
                        const f16x8 a = *(const f16x8*)&As[wr * 64 + mf * 16 + lr][koff];
                        const f16x8 b = *(const f16x8*)&Bs[wc * 64 + nf * 16 + lr][koff];
                        acc[mf][nf] = __builtin_amdgcn_mfma_f32_16x16x32_f16(a, b, acc[mf][nf], 0, 0, 0);
                    } else {
                        const bf16x8 a = *(const bf16x8*)&As[wr * 64 + mf * 16 + lr][koff];
                        const bf16x8 b = *(const bf16x8*)&Bs[wc * 64 + nf * 16 + lr][koff];
                        acc[mf][nf] = __builtin_amdgcn_mfma_f32_16x16x32_bf16(a, b, acc[mf][nf], 0, 0, 0);
                    }
                }
            }
        }
    }

    // epilogue: C/D map col=lane&15, row=4*(lane>>4)+reg (verified)
#pragma unroll
    for (int mf = 0; mf < 4; ++mf)
#pragma unroll
        for (int nf = 0; nf < 4; ++nf)
#pragma unroll
            for (int j = 0; j < 4; ++j) {
                const int gm = m0 + wr * 64 + mf * 16 + lg * 4 + j;
                const int gn = n0 + wc * 64 + nf * 16 + lr;
                const float v = acc[mf][nf][j] + bias[gn];
                if constexpr (MODE == 0) {
                    const int bb = gm >> 10, t = gm & 1023;
                    const int c = gn >> 10, hh = (gn & 1023) >> 6, d = gn & 63;
                    const size_t idx = ((((size_t)bb * HH + hh) << 10) + t) * HDIM + d;
                    if (c == 0) dstH1[idx] = f2bf(v * 0.125f);       // q, pre-scaled
                    else        ((u16*)dstF)[idx] = f2bf(v);         // k bf16
                } else {
                    dstF[(size_t)gm * N + gn] = v;
                }
            }
}

// ---------------------------------------------------------------------------
// Fused pk-GEMM + ktrans (r17) + XCD-chunk swizzle on the GEMM part.
// Blocks [0,256): pk = pe @ Wp^T + bp (fp16 MFMA), kp16 = bf16(pk + k16).
// Blocks [256,1280): k16 -> k16T per-head transpose.
// ---------------------------------------------------------------------------
__global__ __launch_bounds__(256)
void pk_fused_kernel(const u16* __restrict__ Ah, const u16* __restrict__ Bh,
                     const float* __restrict__ bias,
                     u16* __restrict__ kp16, const u16* __restrict__ kaux16,
                     u16* __restrict__ k16T)
{
    __shared__ __align__(16) u16 smem[2 * 128 * 64];   // 32 KB, both paths
    const int tid = threadIdx.x;

    if (blockIdx.x >= 256) {
        // ---- ktrans path ----
        auto tmp = (u16(*)[72])smem;                   // [64][72] = 9 KB
        const int bid = blockIdx.x - 256;
        const int tc = bid & 15, h = (bid >> 4) & 15, b = bid >> 8;
        const size_t hb = ((size_t)(b * HH + h)) << 16;
        const int sr = tid >> 2, sc = (tid & 3) * 8;
        *(bf16x8*)&tmp[sr][sc]      = *(const bf16x8*)&kaux16[hb + (size_t)(tc * 64 + sr) * HDIM + sc];
        *(bf16x8*)&tmp[sr][sc + 32] = *(const bf16x8*)&kaux16[hb + (size_t)(tc * 64 + sr) * HDIM + sc + 32];
        __syncthreads();
#pragma unroll
        for (int half = 0; half < 2; ++half) {
            bf16x8 v;
#pragma unroll
            for (int j = 0; j < 8; ++j) v[j] = (short)tmp[sc + half * 32 + j][sr];
            *(bf16x8*)&k16T[hb + (size_t)sr * TT + tc * 64 + sc + half * 32] = v;
        }
        return;
    }

    // ---- pk GEMM path (fp16, MODE-1 epilogue), XCD-chunk swizzled ----
    auto As = (u16(*)[64])smem;
    auto Bs = (u16(*)[64])(smem + 128 * 64);
    const int w    = tid >> 6;
    const int lane = tid & 63;
    const int lg   = lane >> 4;
    const int lr   = lane & 15;
    const int wr   = w >> 1, wc = w & 1;
    const int fid  = blockIdx.x;                       // 0..255
    const int wg   = ((fid & 7) << 5) | (fid >> 3);    // chunk swizzle, cpx=32
    const int m0   = (wg >> 3) * 128, n0 = (wg & 7) * 128;
    const int K = DD;

    const f32x4 zero = {0.f, 0.f, 0.f, 0.f};
    f32x4 acc[4][4];
#pragma unroll
    for (int i = 0; i < 4; ++i)
#pragma unroll
        for (int j = 0; j < 4; ++j) acc[i][j] = zero;

    const int srow = tid >> 3;
    const int scol = (tid & 7) * 8;
    const int ldr  = w << 3;

    for (int k0 = 0; k0 < K; k0 += 64) {
        __syncthreads();
#pragma unroll
        for (int i = 0; i < 4; ++i) {
            const size_t ga = (size_t)(m0 + i * 32 + srow) * K + k0 + scol;
            const size_t gb = (size_t)(n0 + i * 32 + srow) * K + k0 + scol;
            gload16(&Ah[ga], &As[i * 32 + ldr][0]);
            gload16(&Bh[gb], &Bs[i * 32 + ldr][0]);
        }
        __syncthreads();
#pragma unroll
        for (int kk = 0; kk < 2; ++kk) {
            const int koff = kk * 32 + lg * 8;
#pragma unroll
            for (int mf = 0; mf < 4; ++mf) {
#pragma unroll
                for (int nf = 0; nf < 4; ++nf) {
                    const f16x8 a = *(const f16x8*)&As[wr * 64 + mf * 16 + lr][koff];
                    const f16x8 b = *(const f16x8*)&Bs[wc * 64 + nf * 16 + lr][koff];
                    acc[mf][nf] = __builtin_amdgcn_mfma_f32_16x16x32_f16(a, b, acc[mf][nf], 0, 0, 0);
                }
            }
        }
    }

#pragma unroll
    for (int mf = 0; mf < 4; ++mf)
#pragma unroll
        for (int nf = 0; nf < 4; ++nf)
#pragma unroll
            for (int j = 0; j < 4; ++j) {
                const int gm = m0 + wr * 64 + mf * 16 + lg * 4 + j;
                const int gn = n0 + wc * 64 + nf * 16 + lr;
                const float v = acc[mf][nf][j] + bias[gn];
                const int bb = gm >> 10, t = gm & 1023;
                const int hh = gn >> 6, d = gn & 63;
                const size_t idx = ((((size_t)bb * HH + hh) << 10) + t) * HDIM + d;
                kp16[idx] = f2bf(v + bf2f(kaux16[idx]));             // kp = pk + k(bf16)
            }
}

// ---------------------------------------------------------------------------
// MFMA attention v9 (r15, measured best): 4 waves, QBLK=64, dbuf staging,
// XCD head-group swizzle, vectorized f32x4 NT attn write from wave-local
// bf16 P tile. No setprio (r14: -9us on lockstep). Two-pass recompute (every
// single-exp variant measured worse: r5/r6/r7/r16).
// ---------------------------------------------------------------------------
__global__ __launch_bounds__(256)
void attn_mfma(const u16* __restrict__ qg, const u16* __restrict__ kTg,
               const u16* __restrict__ kpg,
               float* __restrict__ attn, u16* __restrict__ ch)
{
    __shared__ u16 kp_s[2][64][72];   // kp tiles, double-buffered
    __shared__ u16 kT_s[2][64][72];   // kT tiles, double-buffered
    __shared__ u16 P_s[4][16][72];    // per-wave normalized P tile [q][kk]

    const int tid  = threadIdx.x;
    const int w    = tid >> 6;        // wave 0..3
    const int lane = tid & 63;
    const int lg   = lane >> 4;       // 0..3
    const int lr   = lane & 15;       // 0..15

    // XCD swizzle: fid -> (xcd c, slot s); head-group g = c + 8*(s>>4)
    const int fid = blockIdx.x;       // 0..1023
    const int c   = fid & 7;
    const int s   = fid >> 3;         // 0..127
    const int g   = c + 8 * (s >> 4); // 0..63
    const int q0  = (s & 15) * 64;
    const int b   = g >> 4, h = g & 15;
    const size_t hb = ((size_t)(b * HH + h)) << 16;    // head base (T*64 elems)

    bf16x8 qf0, qf1;
    {
        const size_t base = hb + (size_t)(q0 + w * 16 + lr) * HDIM + lg * 8;
        qf0 = *(const bf16x8*)&qg[base];
        qf1 = *(const bf16x8*)&qg[base + 32];
    }

    const int sr = tid >> 2;          // staging row 0..63
    const int sc = (tid & 3) * 8;     // staging col chunk
    bf16x8 ra, rb, rc, rd;            // staging registers

    // ---- pass 1: rowsums ----
    ra = *(const bf16x8*)&kpg[hb + (size_t)sr * HDIM + sc];
    rb = *(const bf16x8*)&kpg[hb + (size_t)sr * HDIM + sc + 32];
    *(bf16x8*)&kp_s[0][sr][sc]      = ra;
    *(bf16x8*)&kp_s[0][sr][sc + 32] = rb;
    __syncthreads();

    float rs[4] = {0.f, 0.f, 0.f, 0.f};
    for (int t = 0; t < TT / 64; ++t) {
        const int cur = t & 1;
        if (t < 15) {   // prefetch next tile into regs
            const size_t nb = hb + (size_t)((t + 1) * 64 + sr) * HDIM;
            ra = *(const bf16x8*)&kpg[nb + sc];
            rb = *(const bf16x8*)&kpg[nb + sc + 32];
        }
#pragma unroll
        for (int ct = 0; ct < 4; ++ct) {
            f32x4 acc = {0.f, 0.f, 0.f, 0.f};
            const bf16x8 b0 = *(const bf16x8*)&kp_s[cur][ct * 16 + lr][lg * 8];
            const bf16x8 b1 = *(const bf16x8*)&kp_s[cur][ct * 16 + lr][lg * 8 + 32];
            acc = __builtin_amdgcn_mfma_f32_16x16x32_bf16(qf0, b0, acc, 0, 0, 0);
            acc = __builtin_amdgcn_mfma_f32_16x16x32_bf16(qf1, b1, acc, 0, 0, 0);
#pragma unroll
            for (int j = 0; j < 4; ++j) rs[j] += __expf(acc[j]);
        }
        if (t < 15) {   // implicit vmcnt wait on ra/rb; write other buffer
            *(bf16x8*)&kp_s[cur ^ 1][sr][sc]      = ra;
            *(bf16x8*)&kp_s[cur ^ 1][sr][sc + 32] = rb;
        }
        __syncthreads();
    }

    // ---- rowsum reduce + pass-2 prologue (loads overlap the reduce) ----
    ra = *(const bf16x8*)&kpg[hb + (size_t)sr * HDIM + sc];
    rb = *(const bf16x8*)&kpg[hb + (size_t)sr * HDIM + sc + 32];
    rc = *(const bf16x8*)&kTg[hb + (size_t)sr * TT + sc];
    rd = *(const bf16x8*)&kTg[hb + (size_t)sr * TT + sc + 32];
#pragma unroll
    for (int off = 1; off < 16; off <<= 1) {
#pragma unroll
        for (int j = 0; j < 4; ++j) rs[j] += __shfl_xor(rs[j], off);
    }
    float ri[4];
#pragma unroll
    for (int j = 0; j < 4; ++j) ri[j] = 1.f / rs[j];
    *(bf16x8*)&kp_s[0][sr][sc]      = ra;
    *(bf16x8*)&kp_s[0][sr][sc + 32] = rb;
    *(bf16x8*)&kT_s[0][sr][sc]      = rc;
    *(bf16x8*)&kT_s[0][sr][sc + 32] = rd;
    __syncthreads();

    // ---- pass 2: P tile + vectorized attn write + PV ----
    f32x4 cacc[4] = {{0,0,0,0},{0,0,0,0},{0,0,0,0},{0,0,0,0}};
    const size_t abase = ((((size_t)b * HH + h) << 10) + q0 + w * 16) << 10;
    const int arow = lane >> 2;       // attn-write row 0..15
    const int acg  = lane & 3;        // attn-write col group

    for (int t = 0; t < TT / 64; ++t) {
        const int cur = t & 1;
        if (t < 15) {   // prefetch next kp + kT tiles into regs
            const size_t nb = hb + (size_t)((t + 1) * 64 + sr) * HDIM;
            ra = *(const bf16x8*)&kpg[nb + sc];
            rb = *(const bf16x8*)&kpg[nb + sc + 32];
            const size_t tb = hb + (size_t)sr * TT + (t + 1) * 64;
            rc = *(const bf16x8*)&kTg[tb + sc];
            rd = *(const bf16x8*)&kTg[tb + sc + 32];
        }
#pragma unroll
        for (int ct = 0; ct < 4; ++ct) {
            f32x4 acc = {0.f, 0.f, 0.f, 0.f};
            const bf16x8 b0 = *(const bf16x8*)&kp_s[cur][ct * 16 + lr][lg * 8];
            const bf16x8 b1 = *(const bf16x8*)&kp_s[cur][ct * 16 + lr][lg * 8 + 32];
            acc = __builtin_amdgcn_mfma_f32_16x16x32_bf16(qf0, b0, acc, 0, 0, 0);
            acc = __builtin_amdgcn_mfma_f32_16x16x32_bf16(qf1, b1, acc, 0, 0, 0);
#pragma unroll
            for (int j = 0; j < 4; ++j) {
                const float p = __expf(acc[j]) * ri[j];
                P_s[w][lg * 4 + j][ct * 16 + lr] = f2bf(p);
            }
        }
        asm volatile("s_waitcnt lgkmcnt(0)" ::: "memory");   // P_s write->read, same wave
        // attn write: wave-local normalized bf16 tile -> f32x4 NT stores
        {
            float* wbase = &attn[abase + (size_t)arow * TT + t * 64 + acg * 4];
#pragma unroll
            for (int kq = 0; kq < 4; ++kq) {
                const u16x4 pv = *(const u16x4*)&P_s[w][arow][kq * 16 + acg * 4];
                f32x4 o = {bf2f(pv[0]), bf2f(pv[1]), bf2f(pv[2]), bf2f(pv[3])};
                __builtin_nontemporal_store(o, (f32x4*)(wbase + kq * 16));
            }
        }
        const bf16x8 pa0 = *(const bf16x8*)&P_s[w][lr][lg * 8];
        const bf16x8 pa1 = *(const bf16x8*)&P_s[w][lr][lg * 8 + 32];
#pragma unroll
        for (int dt = 0; dt < 4; ++dt) {
            const bf16x8 kb0 = *(const bf16x8*)&kT_s[cur][dt * 16 + lr][lg * 8];
            const bf16x8 kb1 = *(const bf16x8*)&kT_s[cur][dt * 16 + lr][lg * 8 + 32];
            cacc[dt] = __builtin_amdgcn_mfma_f32_16x16x32_bf16(pa0, kb0, cacc[dt], 0, 0, 0);
            cacc[dt] = __builtin_amdgcn_mfma_f32_16x16x32_bf16(pa1, kb1, cacc[dt], 0, 0, 0);
        }
        if (t < 15) {
            *(bf16x8*)&kp_s[cur ^ 1][sr][sc]      = ra;
            *(bf16x8*)&kp_s[cur ^ 1][sr][sc + 32] = rb;
            *(bf16x8*)&kT_s[cur ^ 1][sr][sc]      = rc;
            *(bf16x8*)&kT_s[cur ^ 1][sr][sc + 32] = rd;
        }
        __syncthreads();
    }

    // ctx -> bf16 [B][T][H*64]
#pragma unroll
    for (int dt = 0; dt < 4; ++dt)
#pragma unroll
        for (int j = 0; j < 4; ++j) {
            const int qr = q0 + w * 16 + lg * 4 + j;
            ch[(((size_t)b << 10) + qr) * DD + h * HDIM + dt * 16 + lr] = f2bf(cacc[dt][j]);
        }
}

extern "C" void kernel_launch(void* const* d_in, const int* in_sizes, int n_in,
                              void* d_out, int out_size, void* d_ws, size_t ws_size,
                              hipStream_t stream)
{
    const float* x  = (const float*)d_in[0];
    const float* pe = (const float*)d_in[1];
    const float* Wc = (const float*)d_in[2];
    const float* bc = (const float*)d_in[3];
    const float* Wp = (const float*)d_in[4];
    const float* bp = (const float*)d_in[5];
    const float* Wo = (const float*)d_in[6];
    const float* bo = (const float*)d_in[7];

    float* out  = (float*)d_out;                         // [B][T][D]
    float* attn = out + (size_t)MM * DD;                 // [B][H][T][T]

    // 64 MB workspace layout -- fully disjoint regions (chh reuses x16
    // after cqk; everything else has its own home):
    char* ws = (char*)d_ws;
    u16* x16  = (u16*)(ws);                              // [0,8M)    fp16; -> chh after cqk
    u16* pe16 = (u16*)(ws + ((size_t)8 << 20));          // [8,16M)   fp16
    u16* Wc16 = (u16*)(ws + ((size_t)16 << 20));         // [16,20M)  fp16
    u16* Wp16 = (u16*)(ws + ((size_t)20 << 20));         // [20,22M)  fp16
    u16* Wo16 = (u16*)(ws + ((size_t)22 << 20));         // [22,24M)  bf16
    u16* q16  = (u16*)(ws + ((size_t)24 << 20));         // [24,32M)  bf16
    u16* k16  = (u16*)(ws + ((size_t)32 << 20));         // [32,40M)  bf16
    u16* kp16 = (u16*)(ws + ((size_t)40 << 20));         // [40,48M)  bf16
    u16* k16T = (u16*)(ws + ((size_t)56 << 20));         // [56,64M)  bf16
    u16* chh  = x16;                                     // ctx bf16 (x dead after cqk)

    // 1) all input conversions, one launch
    cvt_all_kernel<<<12288, 256, 0, stream>>>(x, x16, pe, pe16, Wc, Wc16,
                                              Wp, Wp16, Wo, Wo16);
    // 2) cqk = x @ Wc^T + bc  (fp16 MFMA, XCD-chunk swizzled; nwg=512 ->
    //    NNSH=4 (nn=16), CPXSH=6 (cpx=64))
    gemm_mfma<true, 0, 4, 6><<<512, 256, 0, stream>>>(
        x16, Wc16, bc, (float*)k16, q16, nullptr, MM, 2048, DD);
    // 3) fused: pk GEMM (swizzled) + ktrans
    pk_fused_kernel<<<1280, 256, 0, stream>>>(
        pe16, Wp16, bp, kp16, k16, k16T);
    // 4) attention: attn f32 + ctx bf16 (r15 structure)
    attn_mfma<<<1024, 256, 0, stream>>>(q16, k16T, kp16, attn, chh);
    // 5) out = ctx @ Wo^T + bo (bf16 MFMA, swizzled; nwg=256 -> NNSH=3, CPXSH=5)
    gemm_mfma<false, 2, 3, 5><<<256, 256, 0, stream>>>(
        chh, Wo16, bo, out, nullptr, nullptr, MM, 1024, DD);
}